// Round 1
// baseline (260.741 us; speedup 1.0000x reference)
//
#include <hip/hip_runtime.h>
#include <hip/hip_bf16.h>
#include <stdint.h>

typedef __bf16 bf16;
typedef __bf16 bf16x8 __attribute__((ext_vector_type(8)));
typedef float  f32x4  __attribute__((ext_vector_type(4)));

#define BM 128
#define BN 128
#define BK 32

__device__ __forceinline__ void gl_lds_16(const bf16* g, bf16* l) {
    __builtin_amdgcn_global_load_lds(
        (__attribute__((address_space(1))) void*)g,
        (__attribute__((address_space(3))) void*)l,
        16, 0, 0);
}

// C[m,n] = sum_k A[m,k] * B[n,k]   (both row-major [rows, K] — "bt" layout)
// OUT_BF16=1 -> write bf16 to Cb; else fp32 to Cf.
template<int OUT_BF16>
__global__ __launch_bounds__(256)
void gemm_bt(const bf16* __restrict__ A, const bf16* __restrict__ Bm,
             bf16* __restrict__ Cb, float* __restrict__ Cf,
             int M, int N, int K)
{
    __shared__ bf16 As[BM * BK];   // 8 KB
    __shared__ bf16 Bs[BN * BK];   // 8 KB

    const int tid  = threadIdx.x;
    const int bm   = blockIdx.x;
    const int bn   = blockIdx.y;
    const int wave = tid >> 6;
    const int lane = tid & 63;
    const int wm   = wave >> 1;    // 0..1
    const int wn   = wave & 1;     // 0..1

    // staging: thread t loads 16B (8 bf16): row = t>>2 (and +64), col = (t&3)*8
    const int srow = tid >> 2;
    const int scol = (tid & 3) << 3;
    const size_t a_off = (size_t)(bm * BM + srow) * K + scol;
    const size_t b_off = (size_t)(bn * BN + srow) * K + scol;
    const int    l_off = srow * BK + scol;          // == tid*8 elements (contig in lane order)

    f32x4 acc[4][4] = {};

    const int fr = lane & 15;
    const int ks = (lane >> 4) << 3;

    for (int k0 = 0; k0 < K; k0 += BK) {
        gl_lds_16(A  + a_off + k0,                 As + l_off);
        gl_lds_16(A  + a_off + (size_t)64 * K + k0, As + l_off + 64 * BK);
        gl_lds_16(Bm + b_off + k0,                 Bs + l_off);
        gl_lds_16(Bm + b_off + (size_t)64 * K + k0, Bs + l_off + 64 * BK);
        __syncthreads();   // drains vmcnt (global_load_lds) before compute

        bf16x8 af[4], bfr[4];
#pragma unroll
        for (int i = 0; i < 4; ++i) {
            af[i]  = *(const bf16x8*)(As + (wm * 64 + i * 16 + fr) * BK + ks);
            bfr[i] = *(const bf16x8*)(Bs + (wn * 64 + i * 16 + fr) * BK + ks);
        }
#pragma unroll
        for (int i = 0; i < 4; ++i)
#pragma unroll
            for (int j = 0; j < 4; ++j)
                acc[i][j] = __builtin_amdgcn_mfma_f32_16x16x32_bf16(af[i], bfr[j], acc[i][j], 0, 0, 0);
        __syncthreads();   // all reads done before next stage overwrites LDS
    }

    // epilogue: C/D layout col = lane&15, row = (lane>>4)*4 + reg
    const int crow = (lane >> 4) << 2;
    const int ccol = lane & 15;
    const int row0 = bm * BM + wm * 64 + crow;
    const int col0 = bn * BN + wn * 64 + ccol;
#pragma unroll
    for (int i = 0; i < 4; ++i)
#pragma unroll
        for (int j = 0; j < 4; ++j)
#pragma unroll
            for (int r = 0; r < 4; ++r) {
                size_t idx = (size_t)(row0 + i * 16 + r) * N + (col0 + j * 16);
                if (OUT_BF16) Cb[idx] = (bf16)acc[i][j][r];
                else          Cf[idx] = acc[i][j][r];
            }
}

__global__ __launch_bounds__(256)
void cvt_f32_bf16(const float* __restrict__ in, bf16* __restrict__ out, int n8)
{
    int i = blockIdx.x * 256 + threadIdx.x;
    if (i >= n8) return;
    const f32x4* p = (const f32x4*)in + 2 * (size_t)i;
    f32x4 a = p[0], b = p[1];
    bf16x8 o;
    o[0] = (bf16)a[0]; o[1] = (bf16)a[1]; o[2] = (bf16)a[2]; o[3] = (bf16)a[3];
    o[4] = (bf16)b[0]; o[5] = (bf16)b[1]; o[6] = (bf16)b[2]; o[7] = (bf16)b[3];
    *((bf16x8*)out + i) = o;
}

// out2[b,s,e] = sum_{j=0..4} filt[j] * v[b, s + shift[h] + j - 2, e], h = e/64
// zero outside [0,4096) per batch. 8 consecutive e per thread (same head).
__global__ __launch_bounds__(256)
void gauss_filter(const bf16* __restrict__ v, bf16* __restrict__ o)
{
    const int idx = blockIdx.x * 256 + threadIdx.x;   // [0, 32768*64)
    const int e8  = idx & 63;
    const int m   = idx >> 6;
    const int s   = m & 4095;
    const int bb  = m >> 12;
    const int h   = e8 >> 3;
    // HEAD_SHIFTS = [0,-1,1,0] * 2
    const int hm  = h & 3;
    const int sh  = (hm == 1) ? -1 : ((hm == 2) ? 1 : 0);

    const float filt[5] = {0.05399096651318806f, 0.24197072451914337f,
                           0.3989422804014327f,
                           0.24197072451914337f, 0.05399096651318806f};
    float acc[8] = {0.f, 0.f, 0.f, 0.f, 0.f, 0.f, 0.f, 0.f};
#pragma unroll
    for (int j = 0; j < 5; ++j) {
        int sp = s + sh + j - 2;
        if (sp >= 0 && sp < 4096) {
            bf16x8 x = *((const bf16x8*)(v + ((size_t)(bb * 4096 + sp)) * 512) + e8);
            float w = filt[j];
#pragma unroll
            for (int d = 0; d < 8; ++d) acc[d] += w * (float)x[d];
        }
    }
    bf16x8 r;
#pragma unroll
    for (int d = 0; d < 8; ++d) r[d] = (bf16)acc[d];
    *((bf16x8*)o + idx) = r;
}

extern "C" void kernel_launch(void* const* d_in, const int* in_sizes, int n_in,
                              void* d_out, int out_size, void* d_ws, size_t ws_size,
                              hipStream_t stream)
{
    const float* values = (const float*)d_in[0];
    // d_in[1] = keys, d_in[2] = queries: unused by the reference path
    const float* w_in   = (const float*)d_in[3];
    const float* w_out  = (const float*)d_in[4];
    float* out = (float*)d_out;

    const int Mrows = 8 * 4096;   // 32768
    const int E = 512;

    // workspace layout (ws need: 1 MB weights + 32 MB vfilt = ~33.6 MB)
    bf16* win_b  = (bf16*)d_ws;                       // 512*512 bf16
    bf16* wout_b = win_b + 512 * 512;
    bf16* vfilt  = wout_b + 512 * 512;                // 32768*512 bf16

    // d_out (64 MB fp32) doubles as scratch until the final GEMM overwrites it:
    bf16* vals_b = (bf16*)d_out;                      // 32 MB: values in bf16
    bf16* v_b    = vals_b + (size_t)Mrows * E;        // 32 MB: projected v in bf16

    cvt_f32_bf16<<<(Mrows * E / 8 + 255) / 256, 256, 0, stream>>>(values, vals_b, Mrows * E / 8);
    cvt_f32_bf16<<<(E * E / 8 + 255) / 256, 256, 0, stream>>>(w_in,  win_b,  E * E / 8);
    cvt_f32_bf16<<<(E * E / 8 + 255) / 256, 256, 0, stream>>>(w_out, wout_b, E * E / 8);

    dim3 g1(Mrows / BM, E / BN);   // 256 x 4
    gemm_bt<1><<<g1, 256, 0, stream>>>(vals_b, win_b, v_b, nullptr, Mrows, E, E);

    gauss_filter<<<Mrows * 64 / 256, 256, 0, stream>>>(v_b, vfilt);

    gemm_bt<0><<<g1, 256, 0, stream>>>(vfilt, wout_b, nullptr, out, Mrows, E, E);
}

// Round 2
// 257.090 us; speedup vs baseline: 1.0142x; 1.0142x over previous
//
#include <hip/hip_runtime.h>
#include <hip/hip_bf16.h>
#include <stdint.h>

typedef __bf16 bf16;
typedef __bf16 bf16x8 __attribute__((ext_vector_type(8)));
typedef float  f32x4  __attribute__((ext_vector_type(4)));

#define BM 128
#define BN 128
#define BK 32
#define E  512
#define SB 4112            // per-batch extended row stride (4098 valid + 14 pad)
#define M1 (8 * SB)        // 32896 = 128 * 257 extended rows
#define M2 32768           // output rows

__device__ __forceinline__ void gl_lds_16(const bf16* g, bf16* l) {
    __builtin_amdgcn_global_load_lds(
        (__attribute__((address_space(1))) void*)g,
        (__attribute__((address_space(3))) void*)l,
        16, 0, 0);
}

// ---------------- GEMM1: C[m,n] = sum_k A[m,k]*B[n,k], bf16 out ----------------
__global__ __launch_bounds__(256)
void gemm_bt_bf16(const bf16* __restrict__ A, const bf16* __restrict__ Bm,
                  bf16* __restrict__ C, int M, int N, int K)
{
    __shared__ bf16 As[BM * BK];
    __shared__ bf16 Bs[BN * BK];

    const int tid  = threadIdx.x;
    const int bm   = blockIdx.x;
    const int bn   = blockIdx.y;
    const int wave = tid >> 6;
    const int lane = tid & 63;
    const int wm   = wave >> 1;
    const int wn   = wave & 1;

    const int srow = tid >> 2;
    const int scol = (tid & 3) << 3;
    const size_t a_off = (size_t)(bm * BM + srow) * K + scol;
    const size_t b_off = (size_t)(bn * BN + srow) * K + scol;
    const int    l_off = srow * BK + scol;

    f32x4 acc[4][4] = {};
    const int fr = lane & 15;
    const int ks = (lane >> 4) << 3;

    for (int k0 = 0; k0 < K; k0 += BK) {
        gl_lds_16(A  + a_off + k0,                  As + l_off);
        gl_lds_16(A  + a_off + (size_t)64 * K + k0, As + l_off + 64 * BK);
        gl_lds_16(Bm + b_off + k0,                  Bs + l_off);
        gl_lds_16(Bm + b_off + (size_t)64 * K + k0, Bs + l_off + 64 * BK);
        __syncthreads();

        bf16x8 af[4], bfr[4];
#pragma unroll
        for (int i = 0; i < 4; ++i) {
            af[i]  = *(const bf16x8*)(As + (wm * 64 + i * 16 + fr) * BK + ks);
            bfr[i] = *(const bf16x8*)(Bs + (wn * 64 + i * 16 + fr) * BK + ks);
        }
#pragma unroll
        for (int i = 0; i < 4; ++i)
#pragma unroll
            for (int j = 0; j < 4; ++j)
                acc[i][j] = __builtin_amdgcn_mfma_f32_16x16x32_bf16(af[i], bfr[j], acc[i][j], 0, 0, 0);
        __syncthreads();
    }

    const int crow = (lane >> 4) << 2;
    const int ccol = lane & 15;
    const int row0 = bm * BM + wm * 64 + crow;
    const int col0 = bn * BN + wn * 64 + ccol;
#pragma unroll
    for (int i = 0; i < 4; ++i)
#pragma unroll
        for (int j = 0; j < 4; ++j)
#pragma unroll
            for (int r = 0; r < 4; ++r)
                C[(size_t)(row0 + i * 16 + r) * N + (col0 + j * 16)] = (bf16)acc[i][j][r];
}

// ------- GEMM2: A gathered with per-head row shift; fp32 out ------------------
// A2[m=(b,s), k] = P[b*SB + s + 1 + sh(k>>6), k];  sh wave-uniform per K-iter.
__global__ __launch_bounds__(256)
void gemm2_gather(const bf16* __restrict__ P, const bf16* __restrict__ Bm,
                  float* __restrict__ C)
{
    __shared__ bf16 As[BM * BK];
    __shared__ bf16 Bs[BN * BK];

    const int tid  = threadIdx.x;
    const int bm   = blockIdx.x;
    const int bn   = blockIdx.y;
    const int wave = tid >> 6;
    const int lane = tid & 63;
    const int wm   = wave >> 1;
    const int wn   = wave & 1;

    const int srow = tid >> 2;
    const int scol = (tid & 3) << 3;

    const int m0 = bm * BM + srow;        // output row for first staged row
    const int m1 = m0 + 64;               // second staged row
    const int prow0 = (m0 >> 12) * SB + (m0 & 4095) + 1;   // extended P row
    const int prow1 = (m1 >> 12) * SB + (m1 & 4095) + 1;

    const size_t b_off = (size_t)(bn * BN + srow) * E + scol;
    const int    l_off = srow * BK + scol;

    f32x4 acc[4][4] = {};
    const int fr = lane & 15;
    const int ks = (lane >> 4) << 3;

    for (int k0 = 0; k0 < E; k0 += BK) {
        const int h3 = (k0 >> 6) & 3;                      // head pattern repeats %4
        const int sh = (h3 == 1) ? -1 : (h3 == 2) ? 1 : 0; // wave-uniform
        gl_lds_16(P + (size_t)(prow0 + sh) * E + scol + k0, As + l_off);
        gl_lds_16(P + (size_t)(prow1 + sh) * E + scol + k0, As + l_off + 64 * BK);
        gl_lds_16(Bm + b_off + k0,                          Bs + l_off);
        gl_lds_16(Bm + b_off + (size_t)64 * E + k0,         Bs + l_off + 64 * BK);
        __syncthreads();

        bf16x8 af[4], bfr[4];
#pragma unroll
        for (int i = 0; i < 4; ++i) {
            af[i]  = *(const bf16x8*)(As + (wm * 64 + i * 16 + fr) * BK + ks);
            bfr[i] = *(const bf16x8*)(Bs + (wn * 64 + i * 16 + fr) * BK + ks);
        }
#pragma unroll
        for (int i = 0; i < 4; ++i)
#pragma unroll
            for (int j = 0; j < 4; ++j)
                acc[i][j] = __builtin_amdgcn_mfma_f32_16x16x32_bf16(af[i], bfr[j], acc[i][j], 0, 0, 0);
        __syncthreads();
    }

    const int crow = (lane >> 4) << 2;
    const int ccol = lane & 15;
    const int row0 = bm * BM + wm * 64 + crow;
    const int col0 = bn * BN + wn * 64 + ccol;
#pragma unroll
    for (int i = 0; i < 4; ++i)
#pragma unroll
        for (int j = 0; j < 4; ++j)
#pragma unroll
            for (int r = 0; r < 4; ++r)
                C[(size_t)(row0 + i * 16 + r) * E + (col0 + j * 16)] = acc[i][j][r];
}

// ------- prefilter: VG[b, r, e] = sum_j filt[j] * values[b, r-1+j-2, e] -------
// r in [0,SB); valid for r in [0,4098) (s' = r-1 in [-1,4096]); else zero.
// Also converts fp32 -> bf16.  One thread per 8 channels.
__global__ __launch_bounds__(256)
void prefilter(const float* __restrict__ vals, bf16* __restrict__ vg)
{
    const int idx = blockIdx.x * 256 + threadIdx.x;    // [0, M1*64)
    const int e8  = idx & 63;
    const int m   = idx >> 6;                          // extended row [0, M1)
    const int b   = m / SB;
    const int r   = m - b * SB;

    const float filt[5] = {0.05399096651318806f, 0.24197072451914337f,
                           0.3989422804014327f,
                           0.24197072451914337f, 0.05399096651318806f};
    float acc[8] = {0.f, 0.f, 0.f, 0.f, 0.f, 0.f, 0.f, 0.f};
    if (r < 4098) {
#pragma unroll
        for (int j = 0; j < 5; ++j) {
            const int sp = r - 3 + j;                  // s' + j - 2
            if (sp >= 0 && sp < 4096) {
                const f32x4* p = (const f32x4*)(vals + ((size_t)(b * 4096 + sp)) * E + e8 * 8);
                f32x4 x0 = p[0], x1 = p[1];
                const float w = filt[j];
                acc[0] += w * x0[0]; acc[1] += w * x0[1];
                acc[2] += w * x0[2]; acc[3] += w * x0[3];
                acc[4] += w * x1[0]; acc[5] += w * x1[1];
                acc[6] += w * x1[2]; acc[7] += w * x1[3];
            }
        }
    }
    bf16x8 o;
#pragma unroll
    for (int d = 0; d < 8; ++d) o[d] = (bf16)acc[d];
    *((bf16x8*)vg + idx) = o;
}

// ------- weight convert: both 512x512 fp32 matrices -> bf16 in one launch -----
__global__ __launch_bounds__(256)
void cvt_weights(const float* __restrict__ w_in, const float* __restrict__ w_out,
                 bf16* __restrict__ win_b, bf16* __restrict__ wout_b)
{
    const int i = blockIdx.x * 256 + threadIdx.x;      // [0, 2*512*512/8)
    const int half = (E * E) / 8;                      // 32768
    const float* src = (i < half) ? w_in : w_out;
    bf16* dst        = (i < half) ? win_b : wout_b;
    const int k = (i < half) ? i : i - half;
    const f32x4* p = (const f32x4*)src + 2 * (size_t)k;
    f32x4 a = p[0], bq = p[1];
    bf16x8 o;
    o[0] = (bf16)a[0]; o[1] = (bf16)a[1]; o[2] = (bf16)a[2]; o[3] = (bf16)a[3];
    o[4] = (bf16)bq[0]; o[5] = (bf16)bq[1]; o[6] = (bf16)bq[2]; o[7] = (bf16)bq[3];
    *((bf16x8*)dst + k) = o;
}

extern "C" void kernel_launch(void* const* d_in, const int* in_sizes, int n_in,
                              void* d_out, int out_size, void* d_ws, size_t ws_size,
                              hipStream_t stream)
{
    const float* values = (const float*)d_in[0];
    // d_in[1]=keys, d_in[2]=queries: unused by the reference path (no QK^T)
    const float* w_in   = (const float*)d_in[3];
    const float* w_out  = (const float*)d_in[4];
    float* out = (float*)d_out;

    // workspace: weights 1 MB + VG 33.7 MB + P 33.7 MB ~= 68.4 MB
    bf16* win_b  = (bf16*)d_ws;                 // 512*512
    bf16* wout_b = win_b + E * E;               // 512*512
    bf16* vg     = wout_b + E * E;              // M1*E
    bf16* Pbuf   = vg + (size_t)M1 * E;         // M1*E

    cvt_weights<<<(2 * E * E / 8) / 256, 256, 0, stream>>>(w_in, w_out, win_b, wout_b);
    prefilter<<<(size_t)M1 * 64 / 256, 256, 0, stream>>>(values, vg);

    dim3 g1(M1 / BM, E / BN);    // 257 x 4
    gemm_bt_bf16<<<g1, 256, 0, stream>>>(vg, win_b, Pbuf, M1, E, E);

    dim3 g2(M2 / BM, E / BN);    // 256 x 4
    gemm2_gather<<<g2, 256, 0, stream>>>(Pbuf, wout_b, out);
}